// Round 2
// baseline (10417.309 us; speedup 1.0000x reference)
//
#include <hip/hip_runtime.h>

#define DEV __device__ __forceinline__

DEV void atomicMaxF(float* addr, float v) {
  if (v >= 0.f) atomicMax((int*)addr, __float_as_int(v));
  else          atomicMin((unsigned int*)addr, __float_as_uint(v));
}

// ---------------------------------------------------------------- K0: init
__global__ void k_init(float* __restrict__ ssum, float* __restrict__ cnt,
                       int* __restrict__ vox2out, unsigned* __restrict__ out,
                       const int* __restrict__ pn0, const int* __restrict__ pn1,
                       const int* __restrict__ pn2, const int* __restrict__ pn3,
                       int N, int out_elems, int4 off4, int4 cap4) {
  const int gid = blockIdx.x * 256 + threadIdx.x;
  const int gs = gridDim.x * 256;
  int ns[4] = {pn0[0], pn1[0], pn2[0], pn3[0]};
  int offs[4] = {off4.x, off4.y, off4.z, off4.w};
  int caps[4] = {cap4.x, cap4.y, cap4.z, cap4.w};
#pragma unroll
  for (int s = 0; s < 4; ++s) {
    int n = min(ns[s], caps[s]);
    float* base = ssum + (size_t)offs[s] * 32;
    int tot = n * 32;
    for (int i = gid; i < tot; i += gs) base[i] = 0.f;
    float* cb = cnt + offs[s];
    for (int i = gid; i < n; i += gs) cb[i] = 0.f;
  }
  for (int i = gid; i < N; i += gs) vox2out[i] = -1;
  for (int i = gid; i < out_elems; i += gs) out[i] = 0xFF800000u;  // -inf
}

// ---------------------------------------------------------------- voxel -> out cell
// all points of one voxel map to the same out cell -> benign race
__global__ void k_v2o(const int* __restrict__ inv_pts, const int* __restrict__ inv_out,
                      int* __restrict__ vox2out, int P) {
  int p = blockIdx.x * 256 + threadIdx.x;
  if (p < P) vox2out[inv_pts[p]] = inv_out[p];
}

// ---------------------------------------------------------------- K1: front
// red = relu(X@W_red+b) (LDS only); y = red@W_att_all; scatter-add y, count.
// LDS: A 9216B + Ws 16384B + Wy 32768B = 58368B (<64KB)
__global__ __launch_bounds__(256, 2) void k_front(
    const float* __restrict__ X, const float* __restrict__ W_red,
    const float* __restrict__ b_red, const float* __restrict__ W_att,
    const int* __restrict__ inv0, const int* __restrict__ inv1,
    const int* __restrict__ inv2, const int* __restrict__ inv3,
    float* __restrict__ ssum, float* __restrict__ cnt,
    int N, int4 off4, int4 cap4) {
  __shared__ float A[64][36];  // X^T tile, then red^T
  __shared__ float Ws[4096];   // W_red [k*64+c]
  __shared__ float Wy[8192];   // W_att natural [s*2048 + k*32 + c]

  const int t = threadIdx.x;
  const int r0 = blockIdx.x * 32;

#pragma unroll
  for (int i = 0; i < 4; ++i) {
    int p = (t + i * 256) * 4;
    *(float4*)&Ws[p] = *(const float4*)(W_red + p);
  }
#pragma unroll
  for (int i = 0; i < 8; ++i) {
    int p = (t + i * 256) * 4;
    *(float4*)&Wy[p] = *(const float4*)(W_att + p);
  }
#pragma unroll
  for (int i = 0; i < 2; ++i) {
    int idx4 = t + i * 256;
    int row = idx4 >> 4, c = (idx4 & 15) * 4;
    int r = r0 + row;
    float4 v = make_float4(0.f, 0.f, 0.f, 0.f);
    if (r < N) v = *(const float4*)(X + (size_t)r * 64 + c);
    A[c + 0][row] = v.x; A[c + 1][row] = v.y;
    A[c + 2][row] = v.z; A[c + 3][row] = v.w;
  }
  __syncthreads();

  const int tx = t & 15, ty = t >> 4;  // cols 4tx.., rows 2ty..
  float acc[2][4] = {};
#pragma unroll
  for (int k = 0; k < 64; ++k) {
    float2 a = *(const float2*)&A[k][2 * ty];
    float4 w = *(const float4*)&Ws[k * 64 + 4 * tx];
    acc[0][0] += a.x * w.x; acc[0][1] += a.x * w.y; acc[0][2] += a.x * w.z; acc[0][3] += a.x * w.w;
    acc[1][0] += a.y * w.x; acc[1][1] += a.y * w.y; acc[1][2] += a.y * w.z; acc[1][3] += a.y * w.w;
  }
  float4 bv = *(const float4*)(b_red + 4 * tx);
  float rv[2][4];
#pragma unroll
  for (int i = 0; i < 2; ++i) {
    rv[i][0] = fmaxf(acc[i][0] + bv.x, 0.f);
    rv[i][1] = fmaxf(acc[i][1] + bv.y, 0.f);
    rv[i][2] = fmaxf(acc[i][2] + bv.z, 0.f);
    rv[i][3] = fmaxf(acc[i][3] + bv.w, 0.f);
  }
  __syncthreads();  // all reads of A done
#pragma unroll
  for (int i = 0; i < 2; ++i) {
    A[4 * tx + 0][2 * ty + i] = rv[i][0];
    A[4 * tx + 1][2 * ty + i] = rv[i][1];
    A[4 * tx + 2][2 * ty + i] = rv[i][2];
    A[4 * tx + 3][2 * ty + i] = rv[i][3];
  }
  __syncthreads();

  // GEMM2: y = red @ W_att_all (128 cols; thread owns 8 cols of ONE scale)
  const int s = tx >> 2;
  const int c0 = (8 * tx) & 31;
  float acc2[2][8] = {};
#pragma unroll
  for (int k = 0; k < 64; ++k) {
    float2 a = *(const float2*)&A[k][2 * ty];
    float4 w0 = *(const float4*)&Wy[s * 2048 + k * 32 + c0];
    float4 w1 = *(const float4*)&Wy[s * 2048 + k * 32 + c0 + 4];
    acc2[0][0] += a.x * w0.x; acc2[0][1] += a.x * w0.y; acc2[0][2] += a.x * w0.z; acc2[0][3] += a.x * w0.w;
    acc2[0][4] += a.x * w1.x; acc2[0][5] += a.x * w1.y; acc2[0][6] += a.x * w1.z; acc2[0][7] += a.x * w1.w;
    acc2[1][0] += a.y * w0.x; acc2[1][1] += a.y * w0.y; acc2[1][2] += a.y * w0.z; acc2[1][3] += a.y * w0.w;
    acc2[1][4] += a.y * w1.x; acc2[1][5] += a.y * w1.y; acc2[1][6] += a.y * w1.z; acc2[1][7] += a.y * w1.w;
  }
  {
    const int* invp = (s == 0) ? inv0 : (s == 1) ? inv1 : (s == 2) ? inv2 : inv3;
    const int offs = (s == 0) ? off4.x : (s == 1) ? off4.y : (s == 2) ? off4.z : off4.w;
    const int caps = (s == 0) ? cap4.x : (s == 1) ? cap4.y : (s == 2) ? cap4.z : cap4.w;
#pragma unroll
    for (int i = 0; i < 2; ++i) {
      int r = r0 + 2 * ty + i;
      if (r < N) {
        int seg = invp[r];
        if ((unsigned)seg < (unsigned)caps) {
          float* b = ssum + ((size_t)offs + seg) * 32 + c0;
#pragma unroll
          for (int j = 0; j < 8; ++j) atomicAdd(b + j, acc2[i][j]);
        }
      }
    }
  }
  if (t < 128) {
    int sc = t >> 5, rl = t & 31;
    int r = r0 + rl;
    if (r < N) {
      const int* invp = (sc == 0) ? inv0 : (sc == 1) ? inv1 : (sc == 2) ? inv2 : inv3;
      const int offs = (sc == 0) ? off4.x : (sc == 1) ? off4.y : (sc == 2) ? off4.z : off4.w;
      const int caps = (sc == 0) ? cap4.x : (sc == 1) ? cap4.y : (sc == 2) ? cap4.z : cap4.w;
      int seg = invp[r];
      if ((unsigned)seg < (unsigned)caps) atomicAdd(&cnt[offs + seg], 1.f);
    }
  }
}

// ---------------------------------------------------------------- K2: segment epilogue
__global__ void k_segep(float* __restrict__ ssum, const float* __restrict__ cnt,
                        const float* __restrict__ b_att,
                        const int* __restrict__ pn0, const int* __restrict__ pn1,
                        const int* __restrict__ pn2, const int* __restrict__ pn3,
                        int4 off4, int4 cap4) {
  const int gid = blockIdx.x * 256 + threadIdx.x;
  const int gs = gridDim.x * 256;
  int ns[4] = {pn0[0], pn1[0], pn2[0], pn3[0]};
  int offs[4] = {off4.x, off4.y, off4.z, off4.w};
  int caps[4] = {cap4.x, cap4.y, cap4.z, cap4.w};
#pragma unroll
  for (int s = 0; s < 4; ++s) {
    int n = min(ns[s], caps[s]);
    float* base = ssum + (size_t)offs[s] * 32;
    const float* cb = cnt + offs[s];
    int tot = n * 32;
    for (int i = gid; i < tot; i += gs) {
      int seg = i >> 5, c = i & 31;
      float v = base[i] / fmaxf(cb[seg], 1.f) + b_att[s * 32 + c];
      base[i] = fmaxf(v, 0.f);
    }
  }
}

// ---------------------------------------------------------------- K3: fused back end
// Recompute red; gather segment feats; attention fuse; out_fc; lin1+relu; lin2+bias;
// scatter-max directly to out. LDS: A 9216 + SP 18432 + B1 4608 + B2 4608 + W 16384
// = 53248B (<64KB, 2 blocks/CU)
__global__ __launch_bounds__(256, 2) void k_back(
    const float* __restrict__ X, const float* __restrict__ W_red,
    const float* __restrict__ b_red, const float* __restrict__ a,
    const int* __restrict__ inv0, const int* __restrict__ inv1,
    const int* __restrict__ inv2, const int* __restrict__ inv3,
    const float* __restrict__ W_fc, const float* __restrict__ W_fcs,
    const float* __restrict__ b_fcs, const float* __restrict__ W_out,
    const float* __restrict__ W_lin1, const float* __restrict__ W_lin2,
    const float* __restrict__ b_lin2, const int* __restrict__ vox2out,
    float* __restrict__ out, int N, int4 off4, int4 cap4) {
  __shared__ float A[64][36];   // X^T then red^T
  __shared__ float SP[4608];    // sf^T[4][32][36]; later f2^T[64][36]@0 + h^T[64][36]@2304
  __shared__ float B1[32][36];  // fS^T then fu^T
  __shared__ float B2[32][36];  // fZ^T
  __shared__ float W[4096];     // weight pool (16KB)

  const int t = threadIdx.x;
  const int r0 = blockIdx.x * 32;
  const int tx = t & 15, ty = t >> 4;

  // ---- stage X^T, W_red; gather per-scale segment features into SP
#pragma unroll
  for (int i = 0; i < 2; ++i) {
    int idx4 = t + i * 256;
    int row = idx4 >> 4, c = (idx4 & 15) * 4;
    int r = r0 + row;
    float4 v = make_float4(0.f, 0.f, 0.f, 0.f);
    if (r < N) v = *(const float4*)(X + (size_t)r * 64 + c);
    A[c + 0][row] = v.x; A[c + 1][row] = v.y;
    A[c + 2][row] = v.z; A[c + 3][row] = v.w;
  }
#pragma unroll
  for (int i = 0; i < 4; ++i) {
    int p = (t + i * 256) * 4;
    *(float4*)&W[p] = *(const float4*)(W_red + p);
  }
#pragma unroll
  for (int s = 0; s < 4; ++s) {
    const int* invp = (s == 0) ? inv0 : (s == 1) ? inv1 : (s == 2) ? inv2 : inv3;
    const int offs = (s == 0) ? off4.x : (s == 1) ? off4.y : (s == 2) ? off4.z : off4.w;
    const int caps = (s == 0) ? cap4.x : (s == 1) ? cap4.y : (s == 2) ? cap4.z : cap4.w;
    int row = t >> 3, c = (t & 7) * 4;
    int r = r0 + row;
    float4 v = make_float4(0.f, 0.f, 0.f, 0.f);
    if (r < N) {
      int seg = invp[r];
      if ((unsigned)seg < (unsigned)caps)
        v = *(const float4*)(a + ((size_t)offs + seg) * 32 + c);
    }
    float* sf = SP + s * 1152;
    sf[(c + 0) * 36 + row] = v.x; sf[(c + 1) * 36 + row] = v.y;
    sf[(c + 2) * 36 + row] = v.z; sf[(c + 3) * 36 + row] = v.w;
  }
  __syncthreads();

  // ---- GEMM1: red
  float accr[2][4] = {};
#pragma unroll
  for (int k = 0; k < 64; ++k) {
    float2 av = *(const float2*)&A[k][2 * ty];
    float4 w = *(const float4*)&W[k * 64 + 4 * tx];
    accr[0][0] += av.x * w.x; accr[0][1] += av.x * w.y; accr[0][2] += av.x * w.z; accr[0][3] += av.x * w.w;
    accr[1][0] += av.y * w.x; accr[1][1] += av.y * w.y; accr[1][2] += av.y * w.z; accr[1][3] += av.y * w.w;
  }
  float4 brv = *(const float4*)(b_red + 4 * tx);
  float rv[2][4];
#pragma unroll
  for (int i = 0; i < 2; ++i) {
    rv[i][0] = fmaxf(accr[i][0] + brv.x, 0.f);
    rv[i][1] = fmaxf(accr[i][1] + brv.y, 0.f);
    rv[i][2] = fmaxf(accr[i][2] + brv.z, 0.f);
    rv[i][3] = fmaxf(accr[i][3] + brv.w, 0.f);
  }
  __syncthreads();  // reads of A, W done
  // red^T into A; featS into B1; W_fc into W
#pragma unroll
  for (int i = 0; i < 2; ++i) {
    A[4 * tx + 0][2 * ty + i] = rv[i][0];
    A[4 * tx + 1][2 * ty + i] = rv[i][1];
    A[4 * tx + 2][2 * ty + i] = rv[i][2];
    A[4 * tx + 3][2 * ty + i] = rv[i][3];
  }
#pragma unroll
  for (int i = 0; i < 4; ++i) {
    int idx = t + i * 256;
    int c = idx >> 5, row = idx & 31;
    B1[c][row] = SP[0 * 1152 + c * 36 + row] + SP[1 * 1152 + c * 36 + row] +
                 SP[2 * 1152 + c * 36 + row] + SP[3 * 1152 + c * 36 + row];
  }
  *(float4*)&W[t * 4] = *(const float4*)(W_fc + t * 4);
  __syncthreads();

  // ---- featZ = relu(featS @ W_fc)  (cols 2tx..2tx+1)
  {
    float acc[2][2] = {};
#pragma unroll
    for (int k = 0; k < 32; ++k) {
      float2 f = *(const float2*)&B1[k][2 * ty];
      float2 w = *(const float2*)&W[k * 32 + 2 * tx];
      acc[0][0] += f.x * w.x; acc[0][1] += f.x * w.y;
      acc[1][0] += f.y * w.x; acc[1][1] += f.y * w.y;
    }
    B2[2 * tx + 0][2 * ty + 0] = fmaxf(acc[0][0], 0.f);
    B2[2 * tx + 1][2 * ty + 0] = fmaxf(acc[0][1], 0.f);
    B2[2 * tx + 0][2 * ty + 1] = fmaxf(acc[1][0], 0.f);
    B2[2 * tx + 1][2 * ty + 1] = fmaxf(acc[1][1], 0.f);
  }
  __syncthreads();  // W (W_fc) reads done, B2 written
#pragma unroll
  for (int i = 0; i < 4; ++i) {
    int p = (t + i * 256) * 4;
    *(float4*)&W[p] = *(const float4*)(W_fcs + p);
  }
  __syncthreads();

  // ---- att = sigmoid(featZ @ W_fcs[s] + b_fcs[s]); fused = sum_s sf[s]*att
  float fused[2][2] = {};
#pragma unroll
  for (int s = 0; s < 4; ++s) {
    float acc[2][2] = {};
#pragma unroll
    for (int k = 0; k < 32; ++k) {
      float2 fz = *(const float2*)&B2[k][2 * ty];
      float2 w = *(const float2*)&W[s * 1024 + k * 32 + 2 * tx];
      acc[0][0] += fz.x * w.x; acc[0][1] += fz.x * w.y;
      acc[1][0] += fz.y * w.x; acc[1][1] += fz.y * w.y;
    }
    float b0 = b_fcs[s * 32 + 2 * tx], b1v = b_fcs[s * 32 + 2 * tx + 1];
    const float* sf = SP + s * 1152;
#pragma unroll
    for (int i = 0; i < 2; ++i) {
      float sg0 = 1.f / (1.f + __expf(-(acc[i][0] + b0)));
      float sg1 = 1.f / (1.f + __expf(-(acc[i][1] + b1v)));
      fused[i][0] += sf[(2 * tx + 0) * 36 + 2 * ty + i] * sg0;
      fused[i][1] += sf[(2 * tx + 1) * 36 + 2 * ty + i] * sg1;
    }
  }
  __syncthreads();  // SP (sf), W (W_fcs), B1 (featS) all dead
  // fu^T into B1; W_out into W
  B1[2 * tx + 0][2 * ty + 0] = fused[0][0];
  B1[2 * tx + 1][2 * ty + 0] = fused[0][1];
  B1[2 * tx + 0][2 * ty + 1] = fused[1][0];
  B1[2 * tx + 1][2 * ty + 1] = fused[1][1];
#pragma unroll
  for (int i = 0; i < 2; ++i) {
    int p = (t + i * 256) * 4;
    *(float4*)&W[p] = *(const float4*)(W_out + p);
  }
  __syncthreads();

  // ---- f2 = fused @ W_out  -> f2^T in SP[0..2304)
  {
    float acc[2][4] = {};
#pragma unroll
    for (int k = 0; k < 32; ++k) {
      float2 fu = *(const float2*)&B1[k][2 * ty];
      float4 w = *(const float4*)&W[k * 64 + 4 * tx];
      acc[0][0] += fu.x * w.x; acc[0][1] += fu.x * w.y; acc[0][2] += fu.x * w.z; acc[0][3] += fu.x * w.w;
      acc[1][0] += fu.y * w.x; acc[1][1] += fu.y * w.y; acc[1][2] += fu.y * w.z; acc[1][3] += fu.y * w.w;
    }
    __syncthreads();  // sf region fully dead (fused done everywhere)
#pragma unroll
    for (int i = 0; i < 2; ++i) {
      SP[(4 * tx + 0) * 36 + 2 * ty + i] = acc[i][0];
      SP[(4 * tx + 1) * 36 + 2 * ty + i] = acc[i][1];
      SP[(4 * tx + 2) * 36 + 2 * ty + i] = acc[i][2];
      SP[(4 * tx + 3) * 36 + 2 * ty + i] = acc[i][3];
    }
  }
  __syncthreads();  // W (W_out) reads done, f2^T ready
#pragma unroll
  for (int i = 0; i < 4; ++i) {  // W_lin1 rows 0..63
    int p = (t + i * 256) * 4;
    *(float4*)&W[p] = *(const float4*)(W_lin1 + p);
  }
  __syncthreads();

  // ---- h = relu(red@W1a + f2@W1b)
  float acch[2][4] = {};
#pragma unroll
  for (int k = 0; k < 64; ++k) {
    float2 r = *(const float2*)&A[k][2 * ty];
    float4 w = *(const float4*)&W[k * 64 + 4 * tx];
    acch[0][0] += r.x * w.x; acch[0][1] += r.x * w.y; acch[0][2] += r.x * w.z; acch[0][3] += r.x * w.w;
    acch[1][0] += r.y * w.x; acch[1][1] += r.y * w.y; acch[1][2] += r.y * w.z; acch[1][3] += r.y * w.w;
  }
  __syncthreads();
#pragma unroll
  for (int i = 0; i < 4; ++i) {  // W_lin1 rows 64..127
    int p = (t + i * 256) * 4;
    *(float4*)&W[p] = *(const float4*)(W_lin1 + 4096 + p);
  }
  __syncthreads();
#pragma unroll
  for (int k = 0; k < 64; ++k) {
    float2 f = *(const float2*)&SP[k * 36 + 2 * ty];
    float4 w = *(const float4*)&W[k * 64 + 4 * tx];
    acch[0][0] += f.x * w.x; acch[0][1] += f.x * w.y; acch[0][2] += f.x * w.z; acch[0][3] += f.x * w.w;
    acch[1][0] += f.y * w.x; acch[1][1] += f.y * w.y; acch[1][2] += f.y * w.z; acch[1][3] += f.y * w.w;
  }
  __syncthreads();  // W reads done
#pragma unroll
  for (int i = 0; i < 2; ++i) {  // h^T into SP[2304..4608)
    SP[2304 + (4 * tx + 0) * 36 + 2 * ty + i] = fmaxf(acch[i][0], 0.f);
    SP[2304 + (4 * tx + 1) * 36 + 2 * ty + i] = fmaxf(acch[i][1], 0.f);
    SP[2304 + (4 * tx + 2) * 36 + 2 * ty + i] = fmaxf(acch[i][2], 0.f);
    SP[2304 + (4 * tx + 3) * 36 + 2 * ty + i] = fmaxf(acch[i][3], 0.f);
  }
#pragma unroll
  for (int i = 0; i < 4; ++i) {
    int p = (t + i * 256) * 4;
    *(float4*)&W[p] = *(const float4*)(W_lin2 + p);
  }
  __syncthreads();

  // ---- proj = h @ W_lin2 + b; scatter-max
  float accp[2][4] = {};
#pragma unroll
  for (int k = 0; k < 64; ++k) {
    float2 h = *(const float2*)&SP[2304 + k * 36 + 2 * ty];
    float4 w = *(const float4*)&W[k * 64 + 4 * tx];
    accp[0][0] += h.x * w.x; accp[0][1] += h.x * w.y; accp[0][2] += h.x * w.z; accp[0][3] += h.x * w.w;
    accp[1][0] += h.y * w.x; accp[1][1] += h.y * w.y; accp[1][2] += h.y * w.z; accp[1][3] += h.y * w.w;
  }
  float4 bl = *(const float4*)(b_lin2 + 4 * tx);
#pragma unroll
  for (int i = 0; i < 2; ++i) {
    int r = r0 + 2 * ty + i;
    if (r < N) {
      int o = vox2out[r];
      if (o >= 0) {
        float* ob = out + (size_t)o * 64 + 4 * tx;
        atomicMaxF(ob + 0, accp[i][0] + bl.x);
        atomicMaxF(ob + 1, accp[i][1] + bl.y);
        atomicMaxF(ob + 2, accp[i][2] + bl.z);
        atomicMaxF(ob + 3, accp[i][3] + bl.w);
      }
    }
  }
}

// ---------------------------------------------------------------- launcher
extern "C" void kernel_launch(void* const* d_in, const int* in_sizes, int n_in,
                              void* d_out, int out_size, void* d_ws, size_t ws_size,
                              hipStream_t stream) {
  const int* inv0 = (const int*)d_in[0];
  const int* pn0 = (const int*)d_in[1];
  const int* inv1 = (const int*)d_in[2];
  const int* pn1 = (const int*)d_in[3];
  const int* inv2 = (const int*)d_in[4];
  const int* pn2 = (const int*)d_in[5];
  const int* inv3 = (const int*)d_in[6];
  const int* pn3 = (const int*)d_in[7];
  const int* inv_pts = (const int*)d_in[8];
  const int* inv_out = (const int*)d_in[9];
  // d_in[10] = n_out (implied by out_size)
  const float* X = (const float*)d_in[11];
  const float* W_red = (const float*)d_in[12];
  const float* b_red = (const float*)d_in[13];
  const float* W_att = (const float*)d_in[14];
  const float* b_att = (const float*)d_in[15];
  const float* W_fcs = (const float*)d_in[16];
  const float* b_fcs = (const float*)d_in[17];
  const float* W_fc = (const float*)d_in[18];
  const float* W_out = (const float*)d_in[19];
  const float* W_lin1 = (const float*)d_in[20];
  const float* W_lin2 = (const float*)d_in[21];
  const float* b_lin2 = (const float*)d_in[22];

  const int N = in_sizes[0];
  const int P = in_sizes[8];

  // per-scale segment-count capacities from grid bounds:
  // s=2: N; s=4: 2*64*64*8=65536; s=6: 2*43*43*6=22188; s=8: 2*32*32*4=8192
  const int cap0 = N, cap1 = 65536, cap2 = 22188, cap3 = 8192;
  const int4 cap4 = make_int4(cap0, cap1, cap2, cap3);
  const int4 off4 = make_int4(0, cap0, cap0 + cap1, cap0 + cap1 + cap2);
  const size_t totRows = (size_t)cap0 + cap1 + cap2 + cap3;

  // ws: ssum[totRows*32] | cnt[totRows] | vox2out[N ints]  (~64 MB at N=400000)
  float* ws = (float*)d_ws;
  float* ssum = ws;
  float* cnt = ssum + totRows * 32;
  int* vox2out = (int*)(cnt + totRows);

  const int nb = (N + 31) / 32;

  k_init<<<1024, 256, 0, stream>>>(ssum, cnt, vox2out, (unsigned*)d_out,
                                   pn0, pn1, pn2, pn3, N, out_size, off4, cap4);
  k_v2o<<<(P + 255) / 256, 256, 0, stream>>>(inv_pts, inv_out, vox2out, P);
  k_front<<<nb, 256, 0, stream>>>(X, W_red, b_red, W_att, inv0, inv1, inv2, inv3,
                                  ssum, cnt, N, off4, cap4);
  k_segep<<<512, 256, 0, stream>>>(ssum, cnt, b_att, pn0, pn1, pn2, pn3, off4, cap4);
  k_back<<<nb, 256, 0, stream>>>(X, W_red, b_red, ssum, inv0, inv1, inv2, inv3,
                                 W_fc, W_fcs, b_fcs, W_out, W_lin1, W_lin2, b_lin2,
                                 vox2out, (float*)d_out, N, off4, cap4);
}

// Round 3
// 3092.278 us; speedup vs baseline: 3.3688x; 3.3688x over previous
//
#include <hip/hip_runtime.h>

typedef unsigned int uint;
typedef unsigned short ushort;

#define DEV __device__ __forceinline__

#define CAP0 16
#define CAP1 32
#define CAP2 64
#define CAP3 128
#define NS1 65536
#define NS2 22188
#define NS3 8192

DEV void atomicMaxF(float* addr, float v) {
  if (v >= 0.f) atomicMax((int*)addr, __float_as_int(v));
  else          atomicMin((unsigned int*)addr, __float_as_uint(v));
}
DEV ushort f2b(float f) {
  uint u = __float_as_uint(f);
  uint r = ((u >> 16) & 1u) + 0x7FFFu;
  return (ushort)((u + r) >> 16);
}
DEV float b2f(ushort h) { return __uint_as_float(((uint)h) << 16); }

// ---------------------------------------------------------------- init
__global__ void k_init(int* __restrict__ cnt, int cntTot, int* __restrict__ vox2out,
                       int N, float* __restrict__ out, int outElems) {
  const int gid = blockIdx.x * 256 + threadIdx.x;
  const int gs = gridDim.x * 256;
  for (int i = gid; i < cntTot; i += gs) cnt[i] = 0;
  for (int i = gid; i < N; i += gs) vox2out[i] = -1;
  const float ninf = __uint_as_float(0xFF800000u);
  for (int i = gid; i < outElems; i += gs) out[i] = ninf;
}

// ---------------------------------------------------------------- voxel -> out cell
__global__ void k_v2o(const int* __restrict__ inv_pts, const int* __restrict__ inv_out,
                      int* __restrict__ vox2out, int P) {
  int p = blockIdx.x * 256 + threadIdx.x;
  if (p < P) vox2out[inv_pts[p]] = inv_out[p];
}

// ---------------------------------------------------------------- red = relu(X@W+b) -> bf16
__global__ __launch_bounds__(256, 2) void k_red(
    const float* __restrict__ X, const float* __restrict__ W_red,
    const float* __restrict__ b_red, ushort* __restrict__ red, int N) {
  __shared__ float A[64][36];
  __shared__ float Ws[4096];
  const int t = threadIdx.x;
  const int r0 = blockIdx.x * 32;
#pragma unroll
  for (int i = 0; i < 4; ++i) {
    int p = (t + i * 256) * 4;
    *(float4*)&Ws[p] = *(const float4*)(W_red + p);
  }
#pragma unroll
  for (int i = 0; i < 2; ++i) {
    int idx4 = t + i * 256;
    int row = idx4 >> 4, c = (idx4 & 15) * 4;
    int r = r0 + row;
    float4 v = make_float4(0.f, 0.f, 0.f, 0.f);
    if (r < N) v = *(const float4*)(X + (size_t)r * 64 + c);
    A[c + 0][row] = v.x; A[c + 1][row] = v.y;
    A[c + 2][row] = v.z; A[c + 3][row] = v.w;
  }
  __syncthreads();
  const int tx = t & 15, ty = t >> 4;
  float acc[2][4] = {};
#pragma unroll
  for (int k = 0; k < 64; ++k) {
    float2 a = *(const float2*)&A[k][2 * ty];
    float4 w = *(const float4*)&Ws[k * 64 + 4 * tx];
    acc[0][0] += a.x * w.x; acc[0][1] += a.x * w.y; acc[0][2] += a.x * w.z; acc[0][3] += a.x * w.w;
    acc[1][0] += a.y * w.x; acc[1][1] += a.y * w.y; acc[1][2] += a.y * w.z; acc[1][3] += a.y * w.w;
  }
  float4 bv = *(const float4*)(b_red + 4 * tx);
#pragma unroll
  for (int i = 0; i < 2; ++i) {
    int r = r0 + 2 * ty + i;
    if (r < N) {
      ushort4 o;
      o.x = f2b(fmaxf(acc[i][0] + bv.x, 0.f));
      o.y = f2b(fmaxf(acc[i][1] + bv.y, 0.f));
      o.z = f2b(fmaxf(acc[i][2] + bv.z, 0.f));
      o.w = f2b(fmaxf(acc[i][3] + bv.w, 0.f));
      *(ushort4*)&red[(size_t)r * 64 + 4 * tx] = o;
    }
  }
}

// ---------------------------------------------------------------- count + slot-fill CSR
__global__ void k_count(const int* __restrict__ inv0, const int* __restrict__ inv1,
                        const int* __restrict__ inv2, const int* __restrict__ inv3,
                        const int* __restrict__ vox2out, int* __restrict__ cnt,
                        int* __restrict__ perm0, int* __restrict__ perm1,
                        int* __restrict__ perm2, int* __restrict__ perm3,
                        int* __restrict__ rank_out, int N, int4 coff) {
  int v = blockIdx.x * 256 + threadIdx.x;
  if (v >= N) return;
  {
    int seg = inv0[v];
    int r = atomicAdd(&cnt[coff.x + seg], 1);
    if (r < CAP0) perm0[(size_t)seg * CAP0 + r] = v;
  }
  {
    int seg = inv1[v];
    int r = atomicAdd(&cnt[coff.y + seg], 1);
    if (r < CAP1) perm1[(size_t)seg * CAP1 + r] = v;
  }
  {
    int seg = inv2[v];
    int r = atomicAdd(&cnt[coff.z + seg], 1);
    if (r < CAP2) perm2[(size_t)seg * CAP2 + r] = v;
  }
  {
    int seg = inv3[v];
    int r = atomicAdd(&cnt[coff.w + seg], 1);
    if (r < CAP3) perm3[(size_t)seg * CAP3 + r] = v;
  }
  int o = vox2out[v];
  if (o >= 0) rank_out[v] = atomicAdd(&cnt[coff.w + NS3 + o], 1);
}

// ---------------------------------------------------------------- scan (3 kernels)
__global__ void k_scan1(const int* __restrict__ c, int n, int* __restrict__ bsum) {
  __shared__ int sd[256];
  const int t = threadIdx.x;
  int base = blockIdx.x * 2048 + t * 8;
  int s = 0;
#pragma unroll
  for (int j = 0; j < 8; ++j) {
    int i = base + j;
    if (i < n) s += c[i];
  }
  sd[t] = s;
  __syncthreads();
  for (int off = 128; off > 0; off >>= 1) {
    if (t < off) sd[t] += sd[t + off];
    __syncthreads();
  }
  if (t == 0) bsum[blockIdx.x] = sd[0];
}

__global__ void k_scan2(int* __restrict__ bsum, int nb, int* __restrict__ meta) {
  __shared__ int sd[256];
  const int t = threadIdx.x;
  int x = (t < nb) ? bsum[t] : 0;
  sd[t] = x;
  __syncthreads();
  for (int off = 1; off < 256; off <<= 1) {
    int v = (t >= off) ? sd[t - off] : 0;
    __syncthreads();
    sd[t] += v;
    __syncthreads();
  }
  bsum[t] = sd[t] - x;  // exclusive
  if (t == 255) meta[0] = sd[255];
}

__global__ void k_scan3(const int* __restrict__ c, int n, const int* __restrict__ bsum,
                        int* __restrict__ start) {
  __shared__ int sd[256];
  const int t = threadIdx.x;
  int base = blockIdx.x * 2048 + t * 8;
  int c8[8];
  int s = 0;
#pragma unroll
  for (int j = 0; j < 8; ++j) {
    int i = base + j;
    c8[j] = (i < n) ? c[i] : 0;
    s += c8[j];
  }
  sd[t] = s;
  __syncthreads();
  for (int off = 1; off < 256; off <<= 1) {
    int v = (t >= off) ? sd[t - off] : 0;
    __syncthreads();
    sd[t] += v;
    __syncthreads();
  }
  int off = bsum[blockIdx.x] + sd[t] - s;
#pragma unroll
  for (int j = 0; j < 8; ++j) {
    int i = base + j;
    if (i < n) start[i] = off;
    off += c8[j];
  }
}

__global__ void k_fill(const int* __restrict__ vox2out, const int* __restrict__ rank_out,
                       const int* __restrict__ start, int* __restrict__ L, int N) {
  int v = blockIdx.x * 256 + threadIdx.x;
  if (v >= N) return;
  int o = vox2out[v];
  if (o >= 0) L[start[o] + rank_out[v]] = v;
}

// ---------------------------------------------------------------- segment features
// 32 segments/block: phase A = gather-mean of red rows (wave per 8 segs),
// phase B = dense (32seg x 64) @ (64 x 32) GEMM + bias + relu -> a (bf16)
__global__ __launch_bounds__(256, 2) void k_segfeat(
    const ushort* __restrict__ red, const int* __restrict__ perm,
    const int* __restrict__ cntS, const float* __restrict__ W_att_s,
    const float* __restrict__ b_att_s, const int* __restrict__ pn,
    ushort* __restrict__ aS, int CAP) {
  __shared__ float meanT[64][33];
  __shared__ float Wa[2048];
  const int t = threadIdx.x;
  const int n = pn[0];
  {
    int p = t * 8;
    *(float4*)&Wa[p] = *(const float4*)(W_att_s + p);
    *(float4*)&Wa[p + 4] = *(const float4*)(W_att_s + p + 4);
  }
  const int lane = t & 63, w = t >> 6;
#pragma unroll
  for (int q = 0; q < 8; ++q) {
    int sloc = w * 8 + q;
    int seg = blockIdx.x * 32 + sloc;
    float mean = 0.f;
    if (seg < n) {
      int m = cntS[seg];
      int mm = min(m, CAP);
      const int* pp = perm + (size_t)seg * CAP;
      float acc = 0.f;
      for (int j = 0; j < mm; ++j) {
        int v = pp[j];
        acc += b2f(red[(size_t)v * 64 + lane]);
      }
      mean = acc / (float)max(m, 1);
    }
    meanT[lane][sloc] = mean;
  }
  __syncthreads();
  const int tx = t & 15, ty = t >> 4;
  float acc[2][2] = {};
#pragma unroll
  for (int k = 0; k < 64; ++k) {
    float m0 = meanT[k][2 * ty];
    float m1 = meanT[k][2 * ty + 1];
    float2 wv = *(const float2*)&Wa[k * 32 + 2 * tx];
    acc[0][0] += m0 * wv.x; acc[0][1] += m0 * wv.y;
    acc[1][0] += m1 * wv.x; acc[1][1] += m1 * wv.y;
  }
  float b0 = b_att_s[2 * tx], b1 = b_att_s[2 * tx + 1];
#pragma unroll
  for (int i = 0; i < 2; ++i) {
    int seg = blockIdx.x * 32 + 2 * ty + i;
    if (seg < n) {
      ushort2 o;
      o.x = f2b(fmaxf(acc[i][0] + b0, 0.f));
      o.y = f2b(fmaxf(acc[i][1] + b1, 0.f));
      *(ushort2*)&aS[(size_t)seg * 32 + 2 * tx] = o;
    }
  }
}

// ---------------------------------------------------------------- fused back end over L-order
// rows = referenced voxels in out-cell order; attention fuse; lin1/lin2; segmented max.
__global__ __launch_bounds__(256, 2) void k_mid(
    const int* __restrict__ L, const int* __restrict__ meta,
    const int* __restrict__ vox2out, const ushort* __restrict__ red,
    const ushort* __restrict__ a, const int* __restrict__ inv0,
    const int* __restrict__ inv1, const int* __restrict__ inv2,
    const int* __restrict__ inv3, const float* __restrict__ W_fc,
    const float* __restrict__ W_fcs, const float* __restrict__ b_fcs,
    const float* __restrict__ W_out, const float* __restrict__ W_lin1,
    const float* __restrict__ W_lin2, const float* __restrict__ b_lin2,
    float* __restrict__ out, int4 aoff) {
  __shared__ float A[64][36];   // red^T; later proj^T
  __shared__ float SP[4608];    // sf^T[4][32][36]; later f2^T@0 + h^T@2304
  __shared__ float B1[32][36];  // featS^T then fu^T
  __shared__ float B2[32][36];  // featZ^T
  __shared__ float W[4096];
  __shared__ int cellid[34];
  __shared__ int vrow[32];

  const int t = threadIdx.x;
  const int i0 = blockIdx.x * 32;
  const int Nref = meta[0];
  if (i0 >= Nref) return;

  if (t < 32) {
    int i = i0 + t;
    int v = (i < Nref) ? L[i] : -1;
    vrow[t] = v;
    cellid[t] = (v >= 0) ? vox2out[v] : -1;
  } else if (t == 32) {
    cellid[32] = (i0 > 0) ? vox2out[L[i0 - 1]] : -1;
  } else if (t == 33) {
    cellid[33] = (i0 + 32 < Nref) ? vox2out[L[i0 + 32]] : -1;
  }
  __syncthreads();

  // stage red^T (bf16 -> f32)
  {
    int row = t >> 3, c8 = (t & 7) * 8;
    int v = vrow[row];
    if (v >= 0) {
      uint4 u = *(const uint4*)&red[(size_t)v * 64 + c8];
      uint uu[4] = {u.x, u.y, u.z, u.w};
#pragma unroll
      for (int j = 0; j < 4; ++j) {
        A[c8 + 2 * j + 0][row] = __uint_as_float(uu[j] << 16);
        A[c8 + 2 * j + 1][row] = __uint_as_float(uu[j] & 0xFFFF0000u);
      }
    } else {
#pragma unroll
      for (int j = 0; j < 8; ++j) A[c8 + j][row] = 0.f;
    }
  }
  // gather per-scale segment features (bf16)
  {
    int row = t >> 3, c4 = (t & 7) * 4;
    int v = vrow[row];
#pragma unroll
    for (int s = 0; s < 4; ++s) {
      float f[4] = {0.f, 0.f, 0.f, 0.f};
      if (v >= 0) {
        const int* invp = (s == 0) ? inv0 : (s == 1) ? inv1 : (s == 2) ? inv2 : inv3;
        int offa = (s == 0) ? aoff.x : (s == 1) ? aoff.y : (s == 2) ? aoff.z : aoff.w;
        int seg = invp[v];
        ushort4 u = *(const ushort4*)&a[((size_t)offa + seg) * 32 + c4];
        f[0] = b2f(u.x); f[1] = b2f(u.y); f[2] = b2f(u.z); f[3] = b2f(u.w);
      }
      float* sf = SP + s * 1152;
      sf[(c4 + 0) * 36 + row] = f[0]; sf[(c4 + 1) * 36 + row] = f[1];
      sf[(c4 + 2) * 36 + row] = f[2]; sf[(c4 + 3) * 36 + row] = f[3];
    }
  }
  *(float4*)&W[t * 4] = *(const float4*)(W_fc + t * 4);  // W_fc 32x32
  __syncthreads();

  const int tx = t & 15, ty = t >> 4;
  // featS = sum_s sf
#pragma unroll
  for (int i = 0; i < 4; ++i) {
    int idx = t + i * 256;
    int c = idx >> 5, row = idx & 31;
    B1[c][row] = SP[0 * 1152 + c * 36 + row] + SP[1 * 1152 + c * 36 + row] +
                 SP[2 * 1152 + c * 36 + row] + SP[3 * 1152 + c * 36 + row];
  }
  __syncthreads();

  // featZ = relu(featS @ W_fc)
  {
    float acc[2][2] = {};
#pragma unroll
    for (int k = 0; k < 32; ++k) {
      float2 f = *(const float2*)&B1[k][2 * ty];
      float2 w = *(const float2*)&W[k * 32 + 2 * tx];
      acc[0][0] += f.x * w.x; acc[0][1] += f.x * w.y;
      acc[1][0] += f.y * w.x; acc[1][1] += f.y * w.y;
    }
    B2[2 * tx + 0][2 * ty + 0] = fmaxf(acc[0][0], 0.f);
    B2[2 * tx + 1][2 * ty + 0] = fmaxf(acc[0][1], 0.f);
    B2[2 * tx + 0][2 * ty + 1] = fmaxf(acc[1][0], 0.f);
    B2[2 * tx + 1][2 * ty + 1] = fmaxf(acc[1][1], 0.f);
  }
  __syncthreads();
#pragma unroll
  for (int i = 0; i < 4; ++i) {
    int p = (t + i * 256) * 4;
    *(float4*)&W[p] = *(const float4*)(W_fcs + p);
  }
  __syncthreads();

  // att + fused
  float fused[2][2] = {};
#pragma unroll
  for (int s = 0; s < 4; ++s) {
    float acc[2][2] = {};
#pragma unroll
    for (int k = 0; k < 32; ++k) {
      float2 fz = *(const float2*)&B2[k][2 * ty];
      float2 w = *(const float2*)&W[s * 1024 + k * 32 + 2 * tx];
      acc[0][0] += fz.x * w.x; acc[0][1] += fz.x * w.y;
      acc[1][0] += fz.y * w.x; acc[1][1] += fz.y * w.y;
    }
    float b0 = b_fcs[s * 32 + 2 * tx], b1v = b_fcs[s * 32 + 2 * tx + 1];
    const float* sf = SP + s * 1152;
#pragma unroll
    for (int i = 0; i < 2; ++i) {
      float sg0 = 1.f / (1.f + __expf(-(acc[i][0] + b0)));
      float sg1 = 1.f / (1.f + __expf(-(acc[i][1] + b1v)));
      fused[i][0] += sf[(2 * tx + 0) * 36 + 2 * ty + i] * sg0;
      fused[i][1] += sf[(2 * tx + 1) * 36 + 2 * ty + i] * sg1;
    }
  }
  __syncthreads();
  B1[2 * tx + 0][2 * ty + 0] = fused[0][0];
  B1[2 * tx + 1][2 * ty + 0] = fused[0][1];
  B1[2 * tx + 0][2 * ty + 1] = fused[1][0];
  B1[2 * tx + 1][2 * ty + 1] = fused[1][1];
#pragma unroll
  for (int i = 0; i < 2; ++i) {
    int p = (t + i * 256) * 4;
    *(float4*)&W[p] = *(const float4*)(W_out + p);
  }
  __syncthreads();

  // f2 = fused @ W_out -> f2^T in SP[0..2304)
  {
    float acc[2][4] = {};
#pragma unroll
    for (int k = 0; k < 32; ++k) {
      float2 fu = *(const float2*)&B1[k][2 * ty];
      float4 w = *(const float4*)&W[k * 64 + 4 * tx];
      acc[0][0] += fu.x * w.x; acc[0][1] += fu.x * w.y; acc[0][2] += fu.x * w.z; acc[0][3] += fu.x * w.w;
      acc[1][0] += fu.y * w.x; acc[1][1] += fu.y * w.y; acc[1][2] += fu.y * w.z; acc[1][3] += fu.y * w.w;
    }
    __syncthreads();
#pragma unroll
    for (int i = 0; i < 2; ++i) {
      SP[(4 * tx + 0) * 36 + 2 * ty + i] = acc[i][0];
      SP[(4 * tx + 1) * 36 + 2 * ty + i] = acc[i][1];
      SP[(4 * tx + 2) * 36 + 2 * ty + i] = acc[i][2];
      SP[(4 * tx + 3) * 36 + 2 * ty + i] = acc[i][3];
    }
  }
  __syncthreads();
#pragma unroll
  for (int i = 0; i < 4; ++i) {
    int p = (t + i * 256) * 4;
    *(float4*)&W[p] = *(const float4*)(W_lin1 + p);
  }
  __syncthreads();

  // h = relu(red@W1a + f2@W1b)
  float acch[2][4] = {};
#pragma unroll
  for (int k = 0; k < 64; ++k) {
    float2 r = *(const float2*)&A[k][2 * ty];
    float4 w = *(const float4*)&W[k * 64 + 4 * tx];
    acch[0][0] += r.x * w.x; acch[0][1] += r.x * w.y; acch[0][2] += r.x * w.z; acch[0][3] += r.x * w.w;
    acch[1][0] += r.y * w.x; acch[1][1] += r.y * w.y; acch[1][2] += r.y * w.z; acch[1][3] += r.y * w.w;
  }
  __syncthreads();
#pragma unroll
  for (int i = 0; i < 4; ++i) {
    int p = (t + i * 256) * 4;
    *(float4*)&W[p] = *(const float4*)(W_lin1 + 4096 + p);
  }
  __syncthreads();
#pragma unroll
  for (int k = 0; k < 64; ++k) {
    float2 f = *(const float2*)&SP[k * 36 + 2 * ty];
    float4 w = *(const float4*)&W[k * 64 + 4 * tx];
    acch[0][0] += f.x * w.x; acch[0][1] += f.x * w.y; acch[0][2] += f.x * w.z; acch[0][3] += f.x * w.w;
    acch[1][0] += f.y * w.x; acch[1][1] += f.y * w.y; acch[1][2] += f.y * w.z; acch[1][3] += f.y * w.w;
  }
  __syncthreads();
#pragma unroll
  for (int i = 0; i < 2; ++i) {
    SP[2304 + (4 * tx + 0) * 36 + 2 * ty + i] = fmaxf(acch[i][0], 0.f);
    SP[2304 + (4 * tx + 1) * 36 + 2 * ty + i] = fmaxf(acch[i][1], 0.f);
    SP[2304 + (4 * tx + 2) * 36 + 2 * ty + i] = fmaxf(acch[i][2], 0.f);
    SP[2304 + (4 * tx + 3) * 36 + 2 * ty + i] = fmaxf(acch[i][3], 0.f);
  }
#pragma unroll
  for (int i = 0; i < 4; ++i) {
    int p = (t + i * 256) * 4;
    *(float4*)&W[p] = *(const float4*)(W_lin2 + p);
  }
  __syncthreads();

  // proj = h @ W_lin2 + b -> proj^T into A
  {
    float acc[2][4] = {};
#pragma unroll
    for (int k = 0; k < 64; ++k) {
      float2 h = *(const float2*)&SP[2304 + k * 36 + 2 * ty];
      float4 w = *(const float4*)&W[k * 64 + 4 * tx];
      acc[0][0] += h.x * w.x; acc[0][1] += h.x * w.y; acc[0][2] += h.x * w.z; acc[0][3] += h.x * w.w;
      acc[1][0] += h.y * w.x; acc[1][1] += h.y * w.y; acc[1][2] += h.y * w.z; acc[1][3] += h.y * w.w;
    }
    float4 bl = *(const float4*)(b_lin2 + 4 * tx);
#pragma unroll
    for (int i = 0; i < 2; ++i) {
      A[4 * tx + 0][2 * ty + i] = acc[i][0] + bl.x;
      A[4 * tx + 1][2 * ty + i] = acc[i][1] + bl.y;
      A[4 * tx + 2][2 * ty + i] = acc[i][2] + bl.z;
      A[4 * tx + 3][2 * ty + i] = acc[i][3] + bl.w;
    }
  }
  __syncthreads();

  // segmented max over out cells; plain write unless run straddles tile edge
  if (t < 64) {
    const int ch = t;
    int cur = cellid[0];
    bool openL = (cur >= 0 && cellid[32] == cur);
    float m = -1e30f;
    for (int r = 0; r < 32; ++r) {
      int c = cellid[r];
      if (c != cur) {
        if (cur >= 0) {
          float* p = out + (size_t)cur * 64 + ch;
          if (openL) atomicMaxF(p, m); else *p = m;
        }
        cur = c; m = -1e30f; openL = false;
      }
      m = fmaxf(m, A[ch][r]);
    }
    if (cur >= 0) {
      bool openR = (cellid[33] == cur);
      float* p = out + (size_t)cur * 64 + ch;
      if (openL || openR) atomicMaxF(p, m); else *p = m;
    }
  }
}

// ---------------------------------------------------------------- launcher
extern "C" void kernel_launch(void* const* d_in, const int* in_sizes, int n_in,
                              void* d_out, int out_size, void* d_ws, size_t ws_size,
                              hipStream_t stream) {
  const int* inv0 = (const int*)d_in[0];
  const int* pn0 = (const int*)d_in[1];
  const int* inv1 = (const int*)d_in[2];
  const int* pn1 = (const int*)d_in[3];
  const int* inv2 = (const int*)d_in[4];
  const int* pn2 = (const int*)d_in[5];
  const int* inv3 = (const int*)d_in[6];
  const int* pn3 = (const int*)d_in[7];
  const int* inv_pts = (const int*)d_in[8];
  const int* inv_out = (const int*)d_in[9];
  const float* X = (const float*)d_in[11];
  const float* W_red = (const float*)d_in[12];
  const float* b_red = (const float*)d_in[13];
  const float* W_att = (const float*)d_in[14];
  const float* b_att = (const float*)d_in[15];
  const float* W_fcs = (const float*)d_in[16];
  const float* b_fcs = (const float*)d_in[17];
  const float* W_fc = (const float*)d_in[18];
  const float* W_out = (const float*)d_in[19];
  const float* W_lin1 = (const float*)d_in[20];
  const float* W_lin2 = (const float*)d_in[21];
  const float* b_lin2 = (const float*)d_in[22];

  const int N = in_sizes[0];
  const int P = in_sizes[8];
  const int n_out = out_size / 64;

  const size_t Rcap = (size_t)N + NS1 + NS2 + NS3;
  const int cntTot = (int)Rcap + n_out;

  // workspace carve-up
  char* w = (char*)d_ws;
  ushort* red = (ushort*)w;           w += (size_t)N * 64 * 2;
  ushort* a = (ushort*)w;             w += Rcap * 32 * 2;
  int* cnt = (int*)w;                 w += (size_t)cntTot * 4;
  int* perm0 = (int*)w;               w += (size_t)N * CAP0 * 4;
  int* perm1 = (int*)w;               w += (size_t)NS1 * CAP1 * 4;
  int* perm2 = (int*)w;               w += (size_t)NS2 * CAP2 * 4;
  int* perm3 = (int*)w;               w += (size_t)NS3 * CAP3 * 4;
  int* vox2out = (int*)w;             w += (size_t)N * 4;
  int* rank_out = (int*)w;            w += (size_t)N * 4;
  int* startO = (int*)w;              w += (size_t)n_out * 4;
  int* L = (int*)w;                   w += (size_t)N * 4;
  int* bsum = (int*)w;                w += 256 * 4;
  int* meta = (int*)w;                w += 16 * 4;

  const int4 coff = make_int4(0, N, N + NS1, N + NS1 + NS2);  // cnt offsets; out at coff.w+NS3
  const int4 aoff = make_int4(0, N, N + NS1, N + NS1 + NS2);  // a row offsets

  const int nb32 = (N + 31) / 32;
  const int nbScan = (n_out + 2047) / 2048;

  k_init<<<1024, 256, 0, stream>>>(cnt, cntTot, vox2out, N, (float*)d_out, out_size);
  k_v2o<<<(P + 255) / 256, 256, 0, stream>>>(inv_pts, inv_out, vox2out, P);
  k_red<<<nb32, 256, 0, stream>>>(X, W_red, b_red, red, N);
  k_count<<<(N + 255) / 256, 256, 0, stream>>>(inv0, inv1, inv2, inv3, vox2out, cnt,
                                               perm0, perm1, perm2, perm3, rank_out,
                                               N, coff);
  k_scan1<<<nbScan, 256, 0, stream>>>(cnt + coff.w + NS3, n_out, bsum);
  k_scan2<<<1, 256, 0, stream>>>(bsum, nbScan, meta);
  k_scan3<<<nbScan, 256, 0, stream>>>(cnt + coff.w + NS3, n_out, bsum, startO);
  k_fill<<<(N + 255) / 256, 256, 0, stream>>>(vox2out, rank_out, startO, L, N);

  k_segfeat<<<nb32, 256, 0, stream>>>(red, perm0, cnt + coff.x, W_att + 0 * 2048,
                                      b_att + 0, pn0, a + (size_t)aoff.x * 32, CAP0);
  k_segfeat<<<(NS1 + 31) / 32, 256, 0, stream>>>(red, perm1, cnt + coff.y, W_att + 1 * 2048,
                                                 b_att + 32, pn1, a + (size_t)aoff.y * 32, CAP1);
  k_segfeat<<<(NS2 + 31) / 32, 256, 0, stream>>>(red, perm2, cnt + coff.z, W_att + 2 * 2048,
                                                 b_att + 64, pn2, a + (size_t)aoff.z * 32, CAP2);
  k_segfeat<<<(NS3 + 31) / 32, 256, 0, stream>>>(red, perm3, cnt + coff.w, W_att + 3 * 2048,
                                                 b_att + 96, pn3, a + (size_t)aoff.w * 32, CAP3);

  k_mid<<<nb32, 256, 0, stream>>>(L, meta, vox2out, red, a, inv0, inv1, inv2, inv3,
                                  W_fc, W_fcs, b_fcs, W_out, W_lin1, W_lin2, b_lin2,
                                  (float*)d_out, aoff);
}